// Round 10
// baseline (293.564 us; speedup 1.0000x reference)
//
#include <hip/hip_runtime.h>
#include <stdint.h>

typedef __attribute__((ext_vector_type(8))) short bf16x8;
typedef __attribute__((ext_vector_type(4))) float f32x4;

#define GM 8192
#define GN 4096
#define GK 4096
#define KT32 (GK / 32)   // 128 K-tiles of 32

__device__ __forceinline__ unsigned short f2bf(float f) {
  union { float f; unsigned int u; } c; c.f = f;
  unsigned int u = c.u;
  unsigned int r = u + 0x7FFFu + ((u >> 16) & 1u);   // round-to-nearest-even
  return (unsigned short)(r >> 16);
}

// ---------------- x (f32) -> bf16, 8 elems/thread ----------------
__global__ __launch_bounds__(256) void cvt_x_kernel(const float* __restrict__ x,
                                                    unsigned short* __restrict__ xb) {
  int i = blockIdx.x * 256 + threadIdx.x;
  const float4* p = (const float4*)x + (size_t)i * 2;
  float4 a = p[0], b = p[1];
  unsigned short t[8] = { f2bf(a.x), f2bf(a.y), f2bf(a.z), f2bf(a.w),
                          f2bf(b.x), f2bf(b.y), f2bf(b.z), f2bf(b.w) };
  int4 pk; __builtin_memcpy(&pk, t, 16);
  ((int4*)xb)[i] = pk;
}

// -------- W_eff = weight + 2 * lora_B @ lora_A -> bf16 --------
__global__ __launch_bounds__(256) void weff_kernel(const float* __restrict__ w,
                                                   const float* __restrict__ lA,
                                                   const float* __restrict__ lB,
                                                   unsigned short* __restrict__ wb) {
  const int K = GK;
  int idx = blockIdx.x * 256 + threadIdx.x;   // over (N/8)*(K/8) = 512*512
  int cg = idx & 511;
  int rg = idx >> 9;
  int i0 = cg << 3;
  int o0 = rg << 3;

  float acc[8][8];
#pragma unroll
  for (int r = 0; r < 8; ++r)
#pragma unroll
    for (int c = 0; c < 8; ++c) acc[r][c] = 0.f;

#pragma unroll
  for (int r = 0; r < 16; ++r) {
    float4 a0 = *(const float4*)(lA + (size_t)r * K + i0);
    float4 a1 = *(const float4*)(lA + (size_t)r * K + i0 + 4);
    float av[8] = { a0.x, a0.y, a0.z, a0.w, a1.x, a1.y, a1.z, a1.w };
#pragma unroll
    for (int row = 0; row < 8; ++row) {
      float b = lB[(size_t)(o0 + row) * 16 + r];
#pragma unroll
      for (int c = 0; c < 8; ++c) acc[row][c] += b * av[c];
    }
  }

#pragma unroll
  for (int row = 0; row < 8; ++row) {
    float4 w0 = *(const float4*)(w + (size_t)(o0 + row) * K + i0);
    float4 w1 = *(const float4*)(w + (size_t)(o0 + row) * K + i0 + 4);
    unsigned short t[8] = {
      f2bf(w0.x + 2.0f * acc[row][0]), f2bf(w0.y + 2.0f * acc[row][1]),
      f2bf(w0.z + 2.0f * acc[row][2]), f2bf(w0.w + 2.0f * acc[row][3]),
      f2bf(w1.x + 2.0f * acc[row][4]), f2bf(w1.y + 2.0f * acc[row][5]),
      f2bf(w1.z + 2.0f * acc[row][6]), f2bf(w1.w + 2.0f * acc[row][7]) };
    int4 pk; __builtin_memcpy(&pk, t, 16);
    *(int4*)(wb + (size_t)(o0 + row) * K + i0) = pk;
  }
}

// ============ 256x256 quad-buffered BK=32 uniform-phase bf16 GEMM: C = A * B^T ============
// 8 waves (2M x 4N), 128x64 C per wave. LDS: 4 buffers x 32 KB (A 16 KB + B 16 KB each),
// 16x32-bf16 subtiles (1 KB), st_16x32 swizzle (pre-swizzled global src, 0 conflicts).
// One phase per K-tile: {stage tile kt+2 (4 gloads) | 12 ds_read of tile kt | vmcnt(4) |
// barrier | 32 independent MFMA (setprio 1)}. Port (96 b128 ~= 1150 cyc/CU) and MFMA
// (~1030 cyc/SIMD) are balanced each phase; staggered lgkm completion overlaps them.
// Publication: phase kt's vmcnt(4) retires tile kt+1 (own loads) + barrier -> phase kt+1
// reads. WAR: buf restaged 4 phases after staging, 2 phases after last read, with >=3
// intervening barriers. Tail: phase KT-2 vmcnt(0), KT-1 no wait.

__device__ __forceinline__ void gload16(const unsigned short* g, char* l) {
  __builtin_amdgcn_global_load_lds((__attribute__((address_space(1))) void*)g,
                                   (__attribute__((address_space(3))) void*)l, 16, 0, 0);
}

__device__ __forceinline__ void bar() {
  asm volatile("" ::: "memory");
  __builtin_amdgcn_s_barrier();
  asm volatile("" ::: "memory");
}

template <int N>
__device__ __forceinline__ void vmwait() {
  if constexpr (N == 0)      asm volatile("s_waitcnt vmcnt(0)" ::: "memory");
  else if constexpr (N == 4) asm volatile("s_waitcnt vmcnt(4)" ::: "memory");
}

#define MFMA_BF16(a, b, c) __builtin_amdgcn_mfma_f32_16x16x32_bf16((a), (b), (c), 0, 0, 0)

// stage one BK=32 K-tile into buffer BUF: wave w stages A subtiles {2w,2w+1} and
// B subtiles {2w,2w+1}; each gload writes one full 1 KB subtile (64 lanes x 16 B).
template <int BUF>
__device__ __forceinline__ void stage_tile(const unsigned short* A, const unsigned short* B,
                                           char* smem, int bm0, int bn0, int w, int lane,
                                           int kt) {
  const int gcol = ((lane & 3) * 8) ^ ((lane & 32) ? 16 : 0);   // pre-swizzled source col
  const int r = lane >> 2;
#pragma unroll
  for (int i = 0; i < 2; ++i) {
    const int sr = 2 * w + i;
    gload16(A + (size_t)(bm0 + sr * 16 + r) * GK + kt * 32 + gcol,
            smem + BUF * 32768 + (sr << 10));
    gload16(B + (size_t)(bn0 + sr * 16 + r) * GK + kt * 32 + gcol,
            smem + BUF * 32768 + 16384 + (sr << 10));
  }
}

__device__ __forceinline__ bf16x8 ldsA(const char* smem, int buf, int sr, int foff) {
  return *(const bf16x8*)(smem + buf * 32768 + (sr << 10) + foff);
}
__device__ __forceinline__ bf16x8 ldsB(const char* smem, int buf, int sr, int foff) {
  return *(const bf16x8*)(smem + buf * 32768 + 16384 + (sr << 10) + foff);
}

// TAIL: 0 = steady (stage kt+2, vmcnt(4)), 1 = kt==KT32-2 (vmcnt(0)), 2 = last (no wait)
template <int BUF, int TAIL>
__device__ __forceinline__ void phase(const unsigned short* __restrict__ A,
                                      const unsigned short* __restrict__ B,
                                      char* smem, int bm0, int bn0, int w, int lane,
                                      int wm, int wn, int foff, int kt,
                                      f32x4 (&acc)[8][4]) {
  if constexpr (TAIL == 0)
    stage_tile<(BUF + 2) & 3>(A, B, smem, bm0, bn0, w, lane, kt + 2);

  bf16x8 av[8], bv[4];
#pragma unroll
  for (int mi = 0; mi < 8; ++mi) av[mi] = ldsA(smem, BUF, wm * 8 + mi, foff);
#pragma unroll
  for (int ni = 0; ni < 4; ++ni) bv[ni] = ldsB(smem, BUF, wn * 4 + ni, foff);

  if constexpr (TAIL == 0)      vmwait<4>();
  else if constexpr (TAIL == 1) vmwait<0>();
  bar();

  __builtin_amdgcn_s_setprio(1);
#pragma unroll
  for (int mi = 0; mi < 8; ++mi)
#pragma unroll
    for (int ni = 0; ni < 4; ++ni)
      acc[mi][ni] = MFMA_BF16(av[mi], bv[ni], acc[mi][ni]);
  __builtin_amdgcn_s_setprio(0);
}

__global__ __launch_bounds__(512, 2) void gemm_bt_kernel(const unsigned short* __restrict__ A,
                                                         const unsigned short* __restrict__ B,
                                                         float* __restrict__ C) {
  __shared__ alignas(16) char smem[131072];

  const int t = threadIdx.x, lane = t & 63, w = t >> 6;
  const int wm = w >> 2, wn = w & 3;     // 2 x 4 wave grid

  // bijective XCD-chunked swizzle: 512 blocks, 512 % 8 == 0
  const int bid = blockIdx.x;
  const int wg  = (bid & 7) * (512 / 8) + (bid >> 3);
  const int bx = wg & 15, by = wg >> 4;
  const int bm0 = by * 256, bn0 = bx * 256;

  // per-lane swizzled fragment byte offset within a 1KB subtile
  int foff = (lane & 15) * 64 + ((lane >> 4) << 4);
  foff ^= ((foff >> 9) & 1) << 5;

  // prologue: tiles 0,1 into bufs 0,1 (8 loads/wave); retire own tile-0 loads; publish.
  stage_tile<0>(A, B, smem, bm0, bn0, w, lane, 0);
  stage_tile<1>(A, B, smem, bm0, bn0, w, lane, 1);
  vmwait<4>();
  bar();

  f32x4 acc[8][4] = {};

  for (int kt = 0; kt < KT32 - 4; kt += 4) {
    phase<0, 0>(A, B, smem, bm0, bn0, w, lane, wm, wn, foff, kt,     acc);
    phase<1, 0>(A, B, smem, bm0, bn0, w, lane, wm, wn, foff, kt + 1, acc);
    phase<2, 0>(A, B, smem, bm0, bn0, w, lane, wm, wn, foff, kt + 2, acc);
    phase<3, 0>(A, B, smem, bm0, bn0, w, lane, wm, wn, foff, kt + 3, acc);
  }
  phase<0, 0>(A, B, smem, bm0, bn0, w, lane, wm, wn, foff, KT32 - 4, acc);
  phase<1, 0>(A, B, smem, bm0, bn0, w, lane, wm, wn, foff, KT32 - 3, acc);
  phase<2, 1>(A, B, smem, bm0, bn0, w, lane, wm, wn, foff, KT32 - 2, acc);
  phase<3, 2>(A, B, smem, bm0, bn0, w, lane, wm, wn, foff, KT32 - 1, acc);

  // epilogue: C/D layout col=lane&15, row=4*(lane>>4)+reg
  const int orow = (lane >> 4) << 2;
#pragma unroll
  for (int mi = 0; mi < 8; ++mi) {
#pragma unroll
    for (int ni = 0; ni < 4; ++ni) {
      float* cp = C + (size_t)(bm0 + wm * 128 + mi * 16 + orow) * GN
                    + (bn0 + wn * 64 + ni * 16 + (lane & 15));
#pragma unroll
      for (int r = 0; r < 4; ++r)
        cp[(size_t)r * GN] = acc[mi][ni][r];
    }
  }
}

extern "C" void kernel_launch(void* const* d_in, const int* in_sizes, int n_in,
                              void* d_out, int out_size, void* d_ws, size_t ws_size,
                              hipStream_t stream) {
  const float* x  = (const float*)d_in[0];   // [4,2048,4096] f32
  const float* w  = (const float*)d_in[1];   // [4096,4096]   f32
  const float* lA = (const float*)d_in[2];   // [16,4096]     f32
  const float* lB = (const float*)d_in[3];   // [4096,16]     f32
  float* out = (float*)d_out;                // [4,2048,4096] f32

  const int M = GM, N = GN, K = GK;

  unsigned short* xb = (unsigned short*)d_ws;          // M*K bf16 = 64MB
  unsigned short* wb = xb + (size_t)M * K;             // N*K bf16 = 32MB

  cvt_x_kernel<<<dim3((M * K / 8) / 256), dim3(256), 0, stream>>>(x, xb);
  weff_kernel<<<dim3((N / 8) * (K / 8) / 256), dim3(256), 0, stream>>>(w, lA, lB, wb);
  gemm_bt_kernel<<<dim3((M / 256) * (N / 256)), dim3(512), 0, stream>>>(xb, wb, out);
}